// Round 11
// baseline (162.402 us; speedup 1.0000x reference)
//
#include <hip/hip_runtime.h>
#include <math.h>

// SpheresRasterizer: B=1, N=1024, H=W=256, K=8.
// Round 10b: R5 structure + NON-TEMPORAL output stores (fix: clang native
// vector type for __builtin_nontemporal_store — HIP float4 is a class type
// and is rejected). Plus one amplified probe dispatch (x24 -> d_ws) to
// surface the warm-rep time + VALUBusy for this exact structure.

#define KPP 8
#define BW  8
#define TS  16

typedef float vf4 __attribute__((ext_vector_type(4)));

static __device__ __forceinline__ void nt_store4(float* p, float a, float b, float c, float d) {
    vf4 v = {a, b, c, d};
    __builtin_nontemporal_store(v, (vf4*)p);
}

template<int REPS>
__global__ __launch_bounds__(256) void sphere_raster_kernel(
    const float* __restrict__ points,   // B*N*3
    const float* __restrict__ radius,   // B*N
    const float* __restrict__ w2v,      // B*16
    const float* __restrict__ proj,     // B*16
    float* __restrict__ out,            // 3 * B*H*W*KPP floats
    int B, int N, int H, int W)
{
    extern __shared__ char smem[];
    float4* cmp  = (float4*)smem;                                     // N+2*BW
    int*    cidx = (int*)(smem + (size_t)(N + 2 * BW) * sizeof(float4));
    __shared__ int wsum[4];

    const int tid      = threadIdx.x;
    const int tilesX   = W / TS;
    const int tilesPer = tilesX * (H / TS);
    const int tile     = blockIdx.x % tilesPer;
    const int b        = blockIdx.x / tilesPer;
    const int tx0      = (tile % tilesX) * TS;
    const int ty0      = (tile / tilesX) * TS;
    const int j        = tx0 + (tid & (TS - 1));
    const int i        = ty0 + (tid >> 4);
    const int lane     = tid & 63;
    const int wid      = tid >> 6;

    const float* M1 = w2v  + (size_t)b * 16;
    const float* M2 = proj + (size_t)b * 16;

    const double halfd = 1.0 - 1.0 / (double)W;
    const double stepd = 2.0 * halfd / (double)(W - 1);
    const float px = (float)(halfd - (double)j * stepd);
    const float py = (float)(halfd - (double)i * stepd);
    const float cx = (float)(halfd - ((double)tx0 + (TS - 1) * 0.5) * stepd);
    const float cy = (float)(halfd - ((double)ty0 + (TS - 1) * 0.5) * stepd);
    const float hext = (float)(((TS - 1) * 0.5 + 1.0) * stepd);  // +1px inflation

    for (int rep = 0; rep < REPS; ++rep) {
        if (REPS > 1) __syncthreads();     // LDS reuse across reps

        // ---- Phase 1: transform 4 points/thread, cull to tile box ----
        const int t0 = tid * 4;
        float4 P[4];
        int keep[4];
        int c = 0;

        const float4* pv = (const float4*)(points + ((size_t)b * N + t0) * 3);
        float4 q0 = pv[0], q1 = pv[1], q2 = pv[2];
        float4 rr = *(const float4*)(radius + (size_t)b * N + t0);
        float xs[4] = {q0.x, q0.w, q1.z, q2.y};
        float ys[4] = {q0.y, q1.x, q1.w, q2.z};
        float zs[4] = {q0.z, q1.y, q2.x, q2.w};
        float rv[4] = {rr.x, rr.y, rr.z, rr.w};

#pragma unroll
        for (int s = 0; s < 4; ++s) {
            float x = xs[s], y = ys[s], z = zs[s];
            float vx = ((x * M1[0] + y * M1[4]) + z * M1[8])  + M1[12];
            float vy = ((x * M1[1] + y * M1[5]) + z * M1[9])  + M1[13];
            float vz = ((x * M1[2] + y * M1[6]) + z * M1[10]) + M1[14];
            float vw = ((x * M1[3] + y * M1[7]) + z * M1[11]) + M1[15];
            float w1 = (fabsf(vw) < 1e-8f) ? 1e-8f : vw;
            vx /= w1; vy /= w1; vz /= w1;
            float sx = ((vx * M2[0] + vy * M2[4]) + vz * M2[8])  + M2[12];
            float sy = ((vx * M2[1] + vy * M2[5]) + vz * M2[9])  + M2[13];
            float sw = ((vx * M2[3] + vy * M2[7]) + vz * M2[11]) + M2[15];
            float w2 = (fabsf(sw) < 1e-8f) ? 1e-8f : sw;
            sx /= w2; sy /= w2;
            float r = rv[s];
            float r2eff = (vz > 0.0f) ? r * r : -1.0f;
            float dxm = fmaxf(0.0f, fabsf(sx - cx) - hext);
            float dym = fmaxf(0.0f, fabsf(sy - cy) - hext);
            float dmin2 = dxm * dxm + dym * dym;
            keep[s] = (dmin2 <= r2eff + 1e-6f) ? 1 : 0;
            P[s] = make_float4(sx, sy, vz, r2eff);
            c += keep[s];
        }

        // ---- order-preserving compaction ----
        int pre = c;
#pragma unroll
        for (int d = 1; d < 64; d <<= 1) {
            int v = __shfl_up(pre, d);
            if (lane >= d) pre += v;
        }
        if (lane == 63) wsum[wid] = pre;
        __syncthreads();
        int wbase = 0, M = 0;
#pragma unroll
        for (int w = 0; w < 4; ++w) {
            int s = wsum[w];
            if (w < wid) wbase += s;
            M += s;
        }
        int pos = wbase + (pre - c);
#pragma unroll
        for (int s = 0; s < 4; ++s) {
            if (keep[s]) { cmp[pos] = P[s]; cidx[pos] = t0 + s; ++pos; }
        }
        const int Mpad = (M + 2 * BW - 1) & ~(2 * BW - 1);
        if (tid < Mpad - M) {
            cmp[M + tid]  = make_float4(0.0f, 0.0f, 0.0f, -1.0f);  // never inside
            cidx[M + tid] = -1;
        }
        __syncthreads();

        // ---- Phase 2: double-buffered 8-wide batched scan ----
        float zb[KPP]; int id[KPP]; float dd[KPP];
#pragma unroll
        for (int k = 0; k < KPP; ++k) { zb[k] = INFINITY; id[k] = -1; dd[k] = -1.0f; }

        auto process = [&](const float4* pp, const int* ii) {
#pragma unroll
            for (int u = 0; u < BW; ++u) {
                float dx = pp[u].x - px;
                float dy = pp[u].y - py;
                float dist2 = __fadd_rn(__fmul_rn(dx, dx), __fmul_rn(dy, dy));
                if ((dist2 <= pp[u].w) && (pp[u].z < zb[KPP - 1])) {
                    float zc = pp[u].z; int ic = ii[u]; float dc = dist2;
#pragma unroll
                    for (int k2 = 0; k2 < KPP; ++k2) {
                        bool lt = (zc < zb[k2]);
                        float tz = zb[k2]; int ti = id[k2]; float td = dd[k2];
                        if (lt) { zb[k2] = zc; id[k2] = ic; dd[k2] = dc; zc = tz; ic = ti; dc = td; }
                    }
                }
            }
        };

        float4 pa[BW]; int ia[BW];
        float4 pb[BW]; int ib[BW];

#pragma unroll
        for (int u = 0; u < BW; ++u) pa[u] = cmp[u];
        {
            int4 t4a = *(const int4*)&cidx[0];
            int4 t4b = *(const int4*)&cidx[4];
            ia[0]=t4a.x; ia[1]=t4a.y; ia[2]=t4a.z; ia[3]=t4a.w;
            ia[4]=t4b.x; ia[5]=t4b.y; ia[6]=t4b.z; ia[7]=t4b.w;
        }

        for (int n = 0; n < Mpad; n += 2 * BW) {
#pragma unroll
            for (int u = 0; u < BW; ++u) pb[u] = cmp[n + BW + u];
            {
                int4 t4a = *(const int4*)&cidx[n + BW];
                int4 t4b = *(const int4*)&cidx[n + BW + 4];
                ib[0]=t4a.x; ib[1]=t4a.y; ib[2]=t4a.z; ib[3]=t4a.w;
                ib[4]=t4b.x; ib[5]=t4b.y; ib[6]=t4b.z; ib[7]=t4b.w;
            }
            process(pa, ia);
            if (n + 2 * BW < Mpad) {
#pragma unroll
                for (int u = 0; u < BW; ++u) pa[u] = cmp[n + 2 * BW + u];
                int4 t4a = *(const int4*)&cidx[n + 2 * BW];
                int4 t4b = *(const int4*)&cidx[n + 2 * BW + 4];
                ia[0]=t4a.x; ia[1]=t4a.y; ia[2]=t4a.z; ia[3]=t4a.w;
                ia[4]=t4b.x; ia[5]=t4b.y; ia[6]=t4b.z; ia[7]=t4b.w;
            }
            process(pb, ib);
        }

        // ---- Phase 3: non-temporal output stores (no L2 write-allocate) ----
        const size_t pix   = ((size_t)b * H + i) * W + j;
        const size_t plane = (size_t)B * H * W * KPP;
        float vidx[KPP], vzbf[KPP], vdst[KPP];
#pragma unroll
        for (int k = 0; k < KPP; ++k) {
            bool valid = (zb[k] != INFINITY);
            vidx[k] = valid ? (float)id[k] : -1.0f;
            vzbf[k] = valid ? zb[k]        : -1.0f;
            vdst[k] = valid ? dd[k]        : -1.0f;
        }
        float* oidx = out + pix * KPP;
        float* ozbf = out + plane + pix * KPP;
        float* odst = out + 2 * plane + pix * KPP;
        nt_store4(oidx,     vidx[0], vidx[1], vidx[2], vidx[3]);
        nt_store4(oidx + 4, vidx[4], vidx[5], vidx[6], vidx[7]);
        nt_store4(ozbf,     vzbf[0], vzbf[1], vzbf[2], vzbf[3]);
        nt_store4(ozbf + 4, vzbf[4], vzbf[5], vzbf[6], vzbf[7]);
        nt_store4(odst,     vdst[0], vdst[1], vdst[2], vdst[3]);
        nt_store4(odst + 4, vdst[4], vdst[5], vdst[6], vdst[7]);
    }
}

extern "C" void kernel_launch(void* const* d_in, const int* in_sizes, int n_in,
                              void* d_out, int out_size, void* d_ws, size_t ws_size,
                              hipStream_t stream) {
    const float* points = (const float*)d_in[0];
    const float* radius = (const float*)d_in[1];
    const float* w2v    = (const float*)d_in[2];
    const float* proj   = (const float*)d_in[3];
    int B = in_sizes[2] / 16;
    if (B < 1) B = 1;
    int N = in_sizes[1] / B;
    int HW = out_size / (3 * B * KPP);
    int H = 1;
    while ((H + 1) * (H + 1) <= HW) ++H;     // integer sqrt
    int W = H;

    int tiles = (W / TS) * (H / TS);
    size_t shmem = (size_t)(N + 2 * BW) * (sizeof(float4) + sizeof(int));

    // Real output (cold path being timed)
    sphere_raster_kernel<1><<<B * tiles, 256, shmem, stream>>>(
        points, radius, w2v, proj, (float*)d_out, B, N, H, W);

    // Amplified probe (x24) -> d_ws: warm-rep time + VALUBusy in rocprof top-5
    sphere_raster_kernel<24><<<B * tiles, 256, shmem, stream>>>(
        points, radius, w2v, proj, (float*)d_ws, B, N, H, W);
}

// Round 12
// 14.139 us; speedup vs baseline: 11.4860x; 11.4860x over previous
//
#include <hip/hip_runtime.h>
#include <math.h>

// SpheresRasterizer: B=1, N=1024, H=W=256, K=8.
// Round 12: clean A/B vs R5 (14.35us): identical structure, ONLY change is
// non-temporal output stores (bypass L2 write-allocate in the harness's
// dirty-L2 replay regime). No probe dispatches this time — single kernel.

#define KPP 8
#define BW  8
#define TS  16

typedef float vf4 __attribute__((ext_vector_type(4)));

static __device__ __forceinline__ void nt_store4(float* p, float a, float b, float c, float d) {
    vf4 v = {a, b, c, d};
    __builtin_nontemporal_store(v, (vf4*)p);
}

__global__ __launch_bounds__(256) void sphere_raster_kernel(
    const float* __restrict__ points,   // B*N*3
    const float* __restrict__ radius,   // B*N
    const float* __restrict__ w2v,      // B*16
    const float* __restrict__ proj,     // B*16
    float* __restrict__ out,            // 3 * B*H*W*KPP floats
    int B, int N, int H, int W)
{
    extern __shared__ char smem[];
    float4* cmp  = (float4*)smem;                                     // N+2*BW
    int*    cidx = (int*)(smem + (size_t)(N + 2 * BW) * sizeof(float4));
    __shared__ int wsum[4];

    const int tid      = threadIdx.x;
    const int tilesX   = W / TS;
    const int tilesPer = tilesX * (H / TS);
    const int tile     = blockIdx.x % tilesPer;
    const int b        = blockIdx.x / tilesPer;
    const int tx0      = (tile % tilesX) * TS;
    const int ty0      = (tile / tilesX) * TS;
    const int j        = tx0 + (tid & (TS - 1));
    const int i        = ty0 + (tid >> 4);
    const int lane     = tid & 63;
    const int wid      = tid >> 6;

    const float* M1 = w2v  + (size_t)b * 16;
    const float* M2 = proj + (size_t)b * 16;

    const double halfd = 1.0 - 1.0 / (double)W;
    const double stepd = 2.0 * halfd / (double)(W - 1);
    const float px = (float)(halfd - (double)j * stepd);
    const float py = (float)(halfd - (double)i * stepd);
    const float cx = (float)(halfd - ((double)tx0 + (TS - 1) * 0.5) * stepd);
    const float cy = (float)(halfd - ((double)ty0 + (TS - 1) * 0.5) * stepd);
    const float hext = (float)(((TS - 1) * 0.5 + 1.0) * stepd);  // +1px inflation

    // ---- Phase 1: transform 4 points/thread, cull to tile box (R5-exact) ----
    const int t0 = tid * 4;
    float4 P[4];
    int keep[4];
    int c = 0;

    const float4* pv = (const float4*)(points + ((size_t)b * N + t0) * 3);
    float4 q0 = pv[0], q1 = pv[1], q2 = pv[2];
    float4 rr = *(const float4*)(radius + (size_t)b * N + t0);
    float xs[4] = {q0.x, q0.w, q1.z, q2.y};
    float ys[4] = {q0.y, q1.x, q1.w, q2.z};
    float zs[4] = {q0.z, q1.y, q2.x, q2.w};
    float rv[4] = {rr.x, rr.y, rr.z, rr.w};

#pragma unroll
    for (int s = 0; s < 4; ++s) {
        float x = xs[s], y = ys[s], z = zs[s];
        float vx = ((x * M1[0] + y * M1[4]) + z * M1[8])  + M1[12];
        float vy = ((x * M1[1] + y * M1[5]) + z * M1[9])  + M1[13];
        float vz = ((x * M1[2] + y * M1[6]) + z * M1[10]) + M1[14];
        float vw = ((x * M1[3] + y * M1[7]) + z * M1[11]) + M1[15];
        float w1 = (fabsf(vw) < 1e-8f) ? 1e-8f : vw;
        vx /= w1; vy /= w1; vz /= w1;
        float sx = ((vx * M2[0] + vy * M2[4]) + vz * M2[8])  + M2[12];
        float sy = ((vx * M2[1] + vy * M2[5]) + vz * M2[9])  + M2[13];
        float sw = ((vx * M2[3] + vy * M2[7]) + vz * M2[11]) + M2[15];
        float w2 = (fabsf(sw) < 1e-8f) ? 1e-8f : sw;
        sx /= w2; sy /= w2;
        float r = rv[s];
        float r2eff = (vz > 0.0f) ? r * r : -1.0f;
        float dxm = fmaxf(0.0f, fabsf(sx - cx) - hext);
        float dym = fmaxf(0.0f, fabsf(sy - cy) - hext);
        float dmin2 = dxm * dxm + dym * dym;
        keep[s] = (dmin2 <= r2eff + 1e-6f) ? 1 : 0;
        P[s] = make_float4(sx, sy, vz, r2eff);
        c += keep[s];
    }

    // ---- order-preserving compaction ----
    int pre = c;
#pragma unroll
    for (int d = 1; d < 64; d <<= 1) {
        int v = __shfl_up(pre, d);
        if (lane >= d) pre += v;
    }
    if (lane == 63) wsum[wid] = pre;
    __syncthreads();
    int wbase = 0, M = 0;
#pragma unroll
    for (int w = 0; w < 4; ++w) {
        int s = wsum[w];
        if (w < wid) wbase += s;
        M += s;
    }
    int pos = wbase + (pre - c);
#pragma unroll
    for (int s = 0; s < 4; ++s) {
        if (keep[s]) { cmp[pos] = P[s]; cidx[pos] = t0 + s; ++pos; }
    }
    const int Mpad = (M + 2 * BW - 1) & ~(2 * BW - 1);
    if (tid < Mpad - M) {
        cmp[M + tid]  = make_float4(0.0f, 0.0f, 0.0f, -1.0f);  // never inside
        cidx[M + tid] = -1;
    }
    __syncthreads();

    // ---- Phase 2: double-buffered 8-wide batched scan ----
    float zb[KPP]; int id[KPP]; float dd[KPP];
#pragma unroll
    for (int k = 0; k < KPP; ++k) { zb[k] = INFINITY; id[k] = -1; dd[k] = -1.0f; }

    auto process = [&](const float4* pp, const int* ii) {
#pragma unroll
        for (int u = 0; u < BW; ++u) {
            float dx = pp[u].x - px;
            float dy = pp[u].y - py;
            float dist2 = __fadd_rn(__fmul_rn(dx, dx), __fmul_rn(dy, dy));
            if ((dist2 <= pp[u].w) && (pp[u].z < zb[KPP - 1])) {
                float zc = pp[u].z; int ic = ii[u]; float dc = dist2;
#pragma unroll
                for (int k2 = 0; k2 < KPP; ++k2) {
                    bool lt = (zc < zb[k2]);
                    float tz = zb[k2]; int ti = id[k2]; float td = dd[k2];
                    if (lt) { zb[k2] = zc; id[k2] = ic; dd[k2] = dc; zc = tz; ic = ti; dc = td; }
                }
            }
        }
    };

    float4 pa[BW]; int ia[BW];
    float4 pb[BW]; int ib[BW];

#pragma unroll
    for (int u = 0; u < BW; ++u) pa[u] = cmp[u];
    {
        int4 t4a = *(const int4*)&cidx[0];
        int4 t4b = *(const int4*)&cidx[4];
        ia[0]=t4a.x; ia[1]=t4a.y; ia[2]=t4a.z; ia[3]=t4a.w;
        ia[4]=t4b.x; ia[5]=t4b.y; ia[6]=t4b.z; ia[7]=t4b.w;
    }

    for (int n = 0; n < Mpad; n += 2 * BW) {
#pragma unroll
        for (int u = 0; u < BW; ++u) pb[u] = cmp[n + BW + u];
        {
            int4 t4a = *(const int4*)&cidx[n + BW];
            int4 t4b = *(const int4*)&cidx[n + BW + 4];
            ib[0]=t4a.x; ib[1]=t4a.y; ib[2]=t4a.z; ib[3]=t4a.w;
            ib[4]=t4b.x; ib[5]=t4b.y; ib[6]=t4b.z; ib[7]=t4b.w;
        }
        process(pa, ia);
        if (n + 2 * BW < Mpad) {
#pragma unroll
            for (int u = 0; u < BW; ++u) pa[u] = cmp[n + 2 * BW + u];
            int4 t4a = *(const int4*)&cidx[n + 2 * BW];
            int4 t4b = *(const int4*)&cidx[n + 2 * BW + 4];
            ia[0]=t4a.x; ia[1]=t4a.y; ia[2]=t4a.z; ia[3]=t4a.w;
            ia[4]=t4b.x; ia[5]=t4b.y; ia[6]=t4b.z; ia[7]=t4b.w;
        }
        process(pb, ib);
    }

    // ---- Phase 3: non-temporal output stores ----
    const size_t pix   = ((size_t)b * H + i) * W + j;
    const size_t plane = (size_t)B * H * W * KPP;
    float vidx[KPP], vzbf[KPP], vdst[KPP];
#pragma unroll
    for (int k = 0; k < KPP; ++k) {
        bool valid = (zb[k] != INFINITY);
        vidx[k] = valid ? (float)id[k] : -1.0f;
        vzbf[k] = valid ? zb[k]        : -1.0f;
        vdst[k] = valid ? dd[k]        : -1.0f;
    }
    float* oidx = out + pix * KPP;
    float* ozbf = out + plane + pix * KPP;
    float* odst = out + 2 * plane + pix * KPP;
    nt_store4(oidx,     vidx[0], vidx[1], vidx[2], vidx[3]);
    nt_store4(oidx + 4, vidx[4], vidx[5], vidx[6], vidx[7]);
    nt_store4(ozbf,     vzbf[0], vzbf[1], vzbf[2], vzbf[3]);
    nt_store4(ozbf + 4, vzbf[4], vzbf[5], vzbf[6], vzbf[7]);
    nt_store4(odst,     vdst[0], vdst[1], vdst[2], vdst[3]);
    nt_store4(odst + 4, vdst[4], vdst[5], vdst[6], vdst[7]);
}

extern "C" void kernel_launch(void* const* d_in, const int* in_sizes, int n_in,
                              void* d_out, int out_size, void* d_ws, size_t ws_size,
                              hipStream_t stream) {
    const float* points = (const float*)d_in[0];
    const float* radius = (const float*)d_in[1];
    const float* w2v    = (const float*)d_in[2];
    const float* proj   = (const float*)d_in[3];
    int B = in_sizes[2] / 16;
    if (B < 1) B = 1;
    int N = in_sizes[1] / B;
    int HW = out_size / (3 * B * KPP);
    int H = 1;
    while ((H + 1) * (H + 1) <= HW) ++H;     // integer sqrt
    int W = H;

    int tiles = (W / TS) * (H / TS);
    size_t shmem = (size_t)(N + 2 * BW) * (sizeof(float4) + sizeof(int));
    sphere_raster_kernel<<<B * tiles, 256, shmem, stream>>>(
        points, radius, w2v, proj, (float*)d_out, B, N, H, W);
}

// Round 13
// 13.621 us; speedup vs baseline: 11.9232x; 1.0381x over previous
//
#include <hip/hip_runtime.h>
#include <math.h>

// SpheresRasterizer: B=1, N=1024, H=W=256, K=8.
// Round 13: R5/R12 skeleton; phase-2 top-K kept as a SINGLE packed u64 key
//   key = (float_bits(z) << 32) | list_pos
// (z>0 finite for all kept candidates -> IEEE bits order-isomorphic to z;
//  list_pos monotone in original index -> tie-break identical to reference).
// Insertion = 8x u64 min/max chain (~40 inst vs ~56); idx/dist2 leave the hot
// loop; dist2 recomputed bit-identically in the epilogue (same inputs, same
// __fmul_rn/__fadd_rn); z unpacked from the key. nt-stores kept from R12.

#define KPP 8
#define BW  8
#define TS  16

typedef float vf4 __attribute__((ext_vector_type(4)));

static __device__ __forceinline__ void nt_store4(float* p, float a, float b, float c, float d) {
    vf4 v = {a, b, c, d};
    __builtin_nontemporal_store(v, (vf4*)p);
}

__global__ __launch_bounds__(256) void sphere_raster_kernel(
    const float* __restrict__ points,   // B*N*3
    const float* __restrict__ radius,   // B*N
    const float* __restrict__ w2v,      // B*16
    const float* __restrict__ proj,     // B*16
    float* __restrict__ out,            // 3 * B*H*W*KPP floats
    int B, int N, int H, int W)
{
    extern __shared__ char smem[];
    float4* cmp  = (float4*)smem;                                     // N+2*BW
    int*    cidx = (int*)(smem + (size_t)(N + 2 * BW) * sizeof(float4));
    __shared__ int wsum[4];

    const int tid      = threadIdx.x;
    const int tilesX   = W / TS;
    const int tilesPer = tilesX * (H / TS);
    const int tile     = blockIdx.x % tilesPer;
    const int b        = blockIdx.x / tilesPer;
    const int tx0      = (tile % tilesX) * TS;
    const int ty0      = (tile / tilesX) * TS;
    const int j        = tx0 + (tid & (TS - 1));
    const int i        = ty0 + (tid >> 4);
    const int lane     = tid & 63;
    const int wid      = tid >> 6;

    const float* M1 = w2v  + (size_t)b * 16;
    const float* M2 = proj + (size_t)b * 16;

    const double halfd = 1.0 - 1.0 / (double)W;
    const double stepd = 2.0 * halfd / (double)(W - 1);
    const float px = (float)(halfd - (double)j * stepd);
    const float py = (float)(halfd - (double)i * stepd);
    const float cx = (float)(halfd - ((double)tx0 + (TS - 1) * 0.5) * stepd);
    const float cy = (float)(halfd - ((double)ty0 + (TS - 1) * 0.5) * stepd);
    const float hext = (float)(((TS - 1) * 0.5 + 1.0) * stepd);  // +1px inflation

    // ---- Phase 1: transform 4 points/thread, cull to tile box (R5-exact) ----
    const int t0 = tid * 4;
    float4 P[4];
    int keep[4];
    int c = 0;

    const float4* pv = (const float4*)(points + ((size_t)b * N + t0) * 3);
    float4 q0 = pv[0], q1 = pv[1], q2 = pv[2];
    float4 rr = *(const float4*)(radius + (size_t)b * N + t0);
    float xs[4] = {q0.x, q0.w, q1.z, q2.y};
    float ys[4] = {q0.y, q1.x, q1.w, q2.z};
    float zs[4] = {q0.z, q1.y, q2.x, q2.w};
    float rv[4] = {rr.x, rr.y, rr.z, rr.w};

#pragma unroll
    for (int s = 0; s < 4; ++s) {
        float x = xs[s], y = ys[s], z = zs[s];
        float vx = ((x * M1[0] + y * M1[4]) + z * M1[8])  + M1[12];
        float vy = ((x * M1[1] + y * M1[5]) + z * M1[9])  + M1[13];
        float vz = ((x * M1[2] + y * M1[6]) + z * M1[10]) + M1[14];
        float vw = ((x * M1[3] + y * M1[7]) + z * M1[11]) + M1[15];
        float w1 = (fabsf(vw) < 1e-8f) ? 1e-8f : vw;
        vx /= w1; vy /= w1; vz /= w1;
        float sx = ((vx * M2[0] + vy * M2[4]) + vz * M2[8])  + M2[12];
        float sy = ((vx * M2[1] + vy * M2[5]) + vz * M2[9])  + M2[13];
        float sw = ((vx * M2[3] + vy * M2[7]) + vz * M2[11]) + M2[15];
        float w2 = (fabsf(sw) < 1e-8f) ? 1e-8f : sw;
        sx /= w2; sy /= w2;
        float r = rv[s];
        float r2eff = (vz > 0.0f) ? r * r : -1.0f;
        float dxm = fmaxf(0.0f, fabsf(sx - cx) - hext);
        float dym = fmaxf(0.0f, fabsf(sy - cy) - hext);
        float dmin2 = dxm * dxm + dym * dym;
        keep[s] = (dmin2 <= r2eff + 1e-6f) ? 1 : 0;
        P[s] = make_float4(sx, sy, vz, r2eff);
        c += keep[s];
    }

    // ---- order-preserving compaction ----
    int pre = c;
#pragma unroll
    for (int d = 1; d < 64; d <<= 1) {
        int v = __shfl_up(pre, d);
        if (lane >= d) pre += v;
    }
    if (lane == 63) wsum[wid] = pre;
    __syncthreads();
    int wbase = 0, M = 0;
#pragma unroll
    for (int w = 0; w < 4; ++w) {
        int s = wsum[w];
        if (w < wid) wbase += s;
        M += s;
    }
    int pos = wbase + (pre - c);
#pragma unroll
    for (int s = 0; s < 4; ++s) {
        if (keep[s]) { cmp[pos] = P[s]; cidx[pos] = t0 + s; ++pos; }
    }
    const int Mpad = (M + 2 * BW - 1) & ~(2 * BW - 1);
    if (tid < Mpad - M) {
        cmp[M + tid]  = make_float4(0.0f, 0.0f, 0.0f, -1.0f);  // r2=-1: never inside
        cidx[M + tid] = -1;
    }
    __syncthreads();

    // ---- Phase 2: double-buffered 8-wide scan, packed-u64 top-K ----
    unsigned long long kb[KPP];
#pragma unroll
    for (int k = 0; k < KPP; ++k) kb[k] = ~0ULL;

    auto process = [&](const float4* pp, int base) {
#pragma unroll
        for (int u = 0; u < BW; ++u) {
            float dx = pp[u].x - px;
            float dy = pp[u].y - py;
            float dist2 = __fadd_rn(__fmul_rn(dx, dx), __fmul_rn(dy, dy));
            unsigned long long key =
                ((unsigned long long)__float_as_uint(pp[u].z) << 32) |
                (unsigned)(base + u);
            if ((dist2 <= pp[u].w) && (key < kb[KPP - 1])) {
                unsigned long long kc = key;
#pragma unroll
                for (int k2 = 0; k2 < KPP; ++k2) {
                    unsigned long long t = kb[k2];
                    bool lt = (kc < t);
                    kb[k2] = lt ? kc : t;   // min
                    kc     = lt ? t  : kc;  // max carries on
                }
            }
        }
    };

    float4 pa[BW];
    float4 pb[BW];

#pragma unroll
    for (int u = 0; u < BW; ++u) pa[u] = cmp[u];

    for (int n = 0; n < Mpad; n += 2 * BW) {
#pragma unroll
        for (int u = 0; u < BW; ++u) pb[u] = cmp[n + BW + u];
        process(pa, n);
        if (n + 2 * BW < Mpad) {
#pragma unroll
            for (int u = 0; u < BW; ++u) pa[u] = cmp[n + 2 * BW + u];
        }
        process(pb, n + BW);
    }

    // ---- Phase 3: unpack keys, recompute dist2 bit-identically, nt-store ----
    const size_t pix   = ((size_t)b * H + i) * W + j;
    const size_t plane = (size_t)B * H * W * KPP;
    float vidx[KPP], vzbf[KPP], vdst[KPP];
#pragma unroll
    for (int k = 0; k < KPP; ++k) {
        unsigned long long key = kb[k];
        bool valid = (key != ~0ULL);
        int p2 = valid ? (int)(key & 0xFFFFFFFFu) : 0;
        float4 p = cmp[p2];
        int idx  = cidx[p2];
        float dx = p.x - px;
        float dy = p.y - py;
        float dist2 = __fadd_rn(__fmul_rn(dx, dx), __fmul_rn(dy, dy));
        float z = __uint_as_float((unsigned)(key >> 32));
        vidx[k] = valid ? (float)idx : -1.0f;
        vzbf[k] = valid ? z          : -1.0f;
        vdst[k] = valid ? dist2      : -1.0f;
    }
    float* oidx = out + pix * KPP;
    float* ozbf = out + plane + pix * KPP;
    float* odst = out + 2 * plane + pix * KPP;
    nt_store4(oidx,     vidx[0], vidx[1], vidx[2], vidx[3]);
    nt_store4(oidx + 4, vidx[4], vidx[5], vidx[6], vidx[7]);
    nt_store4(ozbf,     vzbf[0], vzbf[1], vzbf[2], vzbf[3]);
    nt_store4(ozbf + 4, vzbf[4], vzbf[5], vzbf[6], vzbf[7]);
    nt_store4(odst,     vdst[0], vdst[1], vdst[2], vdst[3]);
    nt_store4(odst + 4, vdst[4], vdst[5], vdst[6], vdst[7]);
}

extern "C" void kernel_launch(void* const* d_in, const int* in_sizes, int n_in,
                              void* d_out, int out_size, void* d_ws, size_t ws_size,
                              hipStream_t stream) {
    const float* points = (const float*)d_in[0];
    const float* radius = (const float*)d_in[1];
    const float* w2v    = (const float*)d_in[2];
    const float* proj   = (const float*)d_in[3];
    int B = in_sizes[2] / 16;
    if (B < 1) B = 1;
    int N = in_sizes[1] / B;
    int HW = out_size / (3 * B * KPP);
    int H = 1;
    while ((H + 1) * (H + 1) <= HW) ++H;     // integer sqrt
    int W = H;

    int tiles = (W / TS) * (H / TS);
    size_t shmem = (size_t)(N + 2 * BW) * (sizeof(float4) + sizeof(int));
    sphere_raster_kernel<<<B * tiles, 256, shmem, stream>>>(
        points, radius, w2v, proj, (float*)d_out, B, N, H, W);
}